// Round 9
// baseline (2589.388 us; speedup 1.0000x reference)
//
#include <hip/hip_runtime.h>

// Problem: B=256, T=512, I=64, H=512.  h_t = tanh(x_t@Wxh + b + h@Whh); out = h_T@fc_w.T + fc_b
//
// R9 = R8 resubmit (R8 bench died on container-infra failure, no counters).
// MFMA over the batch dim.  grid=16 blocks x 512 thr; each block owns 16 batches.
// Per step: H_new[16,512] = tanh(XH_t[16,512] + H[16,512] @ Whh[512,512]) as a wave-level
// MFMA GEMM: 8 waves x 4 j-tiles (16 cols each) x 16 k-steps of mfma_f32_16x16x32_f16.
//   - Whh pre-swizzled to fragment order fp16 in ws (wt_prep): per (jt,kt) a 1KB block of
//     64 lanes x 8 contiguous-k fp16 -> perfectly coalesced, L2-resident (512KB x 2blk/XCD).
//   - h in static LDS (2 x 16 x 536 fp16 = 34KB); A-frag lane stride 1072B -> 2-way bank
//     aliasing only (free, m136).
//   - Fragment layouts: A: m=lane&15, k=8*(lane>>4)+e.  B: n=lane&15, k=8*(lane>>4)+e.
//     C/D (m89-verified): col=lane&15, row=4*(lane>>4)+reg.
//   - Step cost model: max(MFMA ~614, L2-B ~583, epilogue VALU ~512) cy -> ~170-300us.
// Why the pivot: R3-R7 showed the fdot2 path's floor = 256 dot2 + ~192 accvgpr_read
// per thread per step (VALUBusy ~2600 cy/step) -> ~550-850us structural ceiling; the
// "91MB spill" was prologue-only staging (in-loop reloads would need 47TB of L2 traffic).
// Fallbacks: rnn_k4s (857us, ws>=xh) then rnn_fused (ws tiny).

#define BATCH    256
#define TSTEPS   512
#define IDIM     64
#define HDIM     512
#define NTH      512

typedef _Float16 half2_t  __attribute__((ext_vector_type(2)));
typedef _Float16 half8_t  __attribute__((ext_vector_type(8)));
typedef float    f32x4    __attribute__((ext_vector_type(4)));

union H8U {
    half8_t v;
    half2_t p[4];
    uint4   u4;
};

__device__ __forceinline__ float fdot2(half2_t a, half2_t b, float c) {
#if __has_builtin(__builtin_amdgcn_fdot2)
    return __builtin_amdgcn_fdot2(a, b, c, false);
#else
    return c + (float)a[0] * (float)b[0] + (float)a[1] * (float)b[1];
#endif
}

__device__ __forceinline__ float fast_tanh(float x) {
    float e = __builtin_amdgcn_exp2f(x * 2.88539008177792681472f);
    return 1.0f - 2.0f * __builtin_amdgcn_rcpf(e + 1.0f);
}

// ============================= xh precompute (unchanged) =============================
#define XH_ROWS 16
__global__ __launch_bounds__(NTH, 4)
void xh_gemm(const float* __restrict__ x, const float* __restrict__ Wxh,
             const float* __restrict__ bias, _Float16* __restrict__ xh)
{
    const int j = threadIdx.x;
    const size_t r0 = (size_t)blockIdx.x * XH_ROWS;
    float wcol[IDIM];
#pragma unroll
    for (int i = 0; i < IDIM; ++i) wcol[i] = Wxh[(size_t)i * HDIM + j];
    const float bj = bias[j];
#pragma unroll
    for (int r = 0; r < XH_ROWS; ++r) {
        const float* xr = x + (r0 + r) * IDIM;   // wave-uniform address -> s_loads
        float acc = bj;
#pragma unroll
        for (int i = 0; i < IDIM; ++i) acc += xr[i] * wcol[i];
        xh[(r0 + r) * HDIM + j] = (_Float16)acc;
    }
}

// ============================= Whh -> B-fragment swizzle =============================
// wt[((jt*16 + kt)*64 + l)*8 + e] = (fp16) Whh[(32*kt + 8*(l>>4) + e)*512 + 16*jt + (l&15)]
// 32 jt x 16 kt x 64 lanes x 8 elems = 512x512.  One-time, ~1MB read.
#define KT    16
#define NJT   32
__global__ __launch_bounds__(NTH)
void wt_prep(const float* __restrict__ Whh, _Float16* __restrict__ wt)
{
    const int id = blockIdx.x * NTH + threadIdx.x;   // [0, 32768)
    const int l  = id & 63;
    const int kt = (id >> 6) & 15;
    const int jt = id >> 10;
    const int n     = 16 * jt + (l & 15);
    const int kbase = 32 * kt + 8 * (l >> 4);
    _Float16 v[8];
#pragma unroll
    for (int e = 0; e < 8; ++e)
        v[e] = (_Float16)Whh[(size_t)(kbase + e) * HDIM + n];
    *reinterpret_cast<uint4*>(wt + (size_t)id * 8) = *reinterpret_cast<const uint4*>(v);
}

// ============================= MFMA RNN =============================
#define MPB   16           // batches per block
#define NBLK  (BATCH / MPB)
#define HS    536          // padded h row stride in fp16 (1072B: 16B-aligned, 2-way banks)

__global__ __attribute__((amdgpu_flat_work_group_size(NTH, NTH), amdgpu_waves_per_eu(2, 2)))
void rnn_mfma(const _Float16* __restrict__ xh,   // (B*T, H) fp16, bias folded in
              const _Float16* __restrict__ wt,   // B-fragment-swizzled Whh, fp16
              const float* __restrict__ fcw,
              const float* __restrict__ fcb,
              float* __restrict__ out)
{
    __shared__ _Float16 hbuf[2][MPB][HS];

    const int tid  = threadIdx.x;
    const int l    = tid & 63;          // lane
    const int w    = tid >> 6;          // wave 0..7
    const int b0   = blockIdx.x * MPB;

    const int row_c = l & 15;           // A-frag m / C-frag col
    const int kgrp  = l >> 4;           // 0..3
    const int erow0 = 4 * kgrp;         // C-frag rows erow0..erow0+3

    // zero h buffer 0 (h_0 = 0); pads included, harmless
    for (int i = tid; i < MPB * HS; i += NTH) hbuf[0][0][i] = (_Float16)0.0f;

    // per-lane constants
    int cols[4];
    const half8_t* wb[4];
#pragma unroll
    for (int i = 0; i < 4; ++i) {
        const int jt = 4 * w + i;
        cols[i] = 16 * jt + row_c;
        wb[i]   = reinterpret_cast<const half8_t*>(wt + ((size_t)jt * KT * 64 + l) * 8);
    }
    const _Float16* xrow[4];
#pragma unroll
    for (int r = 0; r < 4; ++r)
        xrow[r] = xh + (size_t)(b0 + erow0 + r) * TSTEPS * HDIM;

    __syncthreads();

#pragma unroll 1
    for (int t = 0; t < TSTEPS; ++t) {
        const _Float16 (*hb)[HS] = hbuf[t & 1];
        _Float16 (*hn)[HS]       = hbuf[(t & 1) ^ 1];

        // xh for this step's epilogue (issued early, consumed after the k-loop)
        float xv[4][4];
        const size_t toff = (size_t)t * HDIM;
#pragma unroll
        for (int i = 0; i < 4; ++i)
#pragma unroll
            for (int r = 0; r < 4; ++r)
                xv[i][r] = (float)xrow[r][toff + cols[i]];

        f32x4 acc0 = {0.f, 0.f, 0.f, 0.f};
        f32x4 acc1 = {0.f, 0.f, 0.f, 0.f};
        f32x4 acc2 = {0.f, 0.f, 0.f, 0.f};
        f32x4 acc3 = {0.f, 0.f, 0.f, 0.f};

#pragma unroll
        for (int kt = 0; kt < KT; ++kt) {
            const half8_t a = *reinterpret_cast<const half8_t*>(
                &hb[row_c][32 * kt + 8 * kgrp]);
            const half8_t bf0 = wb[0][(size_t)kt * 64];
            const half8_t bf1 = wb[1][(size_t)kt * 64];
            const half8_t bf2 = wb[2][(size_t)kt * 64];
            const half8_t bf3 = wb[3][(size_t)kt * 64];
            acc0 = __builtin_amdgcn_mfma_f32_16x16x32_f16(a, bf0, acc0, 0, 0, 0);
            acc1 = __builtin_amdgcn_mfma_f32_16x16x32_f16(a, bf1, acc1, 0, 0, 0);
            acc2 = __builtin_amdgcn_mfma_f32_16x16x32_f16(a, bf2, acc2, 0, 0, 0);
            acc3 = __builtin_amdgcn_mfma_f32_16x16x32_f16(a, bf3, acc3, 0, 0, 0);
        }

        // epilogue: h_new[row][col] = tanh(acc + xh)
#pragma unroll
        for (int r = 0; r < 4; ++r) {
            hn[erow0 + r][cols[0]] = (_Float16)fast_tanh(acc0[r] + xv[0][r]);
            hn[erow0 + r][cols[1]] = (_Float16)fast_tanh(acc1[r] + xv[1][r]);
            hn[erow0 + r][cols[2]] = (_Float16)fast_tanh(acc2[r] + xv[2][r]);
            hn[erow0 + r][cols[3]] = (_Float16)fast_tanh(acc3[r] + xv[3][r]);
        }
        __syncthreads();
    }

    // ---- output: T even -> final h in hbuf[0].  32 threads per batch. ----
    const int m = tid >> 5;
    const int s = tid & 31;
    float p = 0.f;
    for (int j = s; j < HDIM; j += 32) p += (float)hbuf[0][m][j] * fcw[j];
#pragma unroll
    for (int off = 16; off >= 1; off >>= 1) p += __shfl_down(p, off, 32);
    if (s == 0) out[b0 + m] = p + fcb[0];
}

// ============================= k4s fallback (R4, 857us, needs ws >= xh) ======================
#define K4_RP      48
#define K4_NW      (4 * K4_RP)
#define K4_STR     17
#define K4_W_BYTES (NTH * K4_STR * 16)
#define K4_HB_OFF   K4_W_BYTES
#define K4_HB_STRIDE 1152
#define K4_RED_OFF  (K4_HB_OFF + 2 * K4_HB_STRIDE)
#define K4_SMEM_BYTES (K4_RED_OFF + 64)

__device__ __forceinline__ float quad_sum(float x) {
    union { float f; int i; } a, b;
    a.f = x;
    b.i = __builtin_amdgcn_update_dpp(0, a.i, 0xB1, 0xF, 0xF, true);
    a.f += b.f;
    b.i = __builtin_amdgcn_update_dpp(0, a.i, 0x4E, 0xF, 0xF, true);
    a.f += b.f;
    return a.f;
}

__global__ __attribute__((amdgpu_flat_work_group_size(NTH, NTH), amdgpu_waves_per_eu(2, 2)))
void rnn_k4s(const _Float16* __restrict__ xh, const float* __restrict__ Whh,
             const float* __restrict__ fcw, const float* __restrict__ fcb,
             float* __restrict__ out)
{
    extern __shared__ char smem[];
    uint4* ldsW = reinterpret_cast<uint4*>(smem);
    float* red  = reinterpret_cast<float*>(smem + K4_RED_OFF);

    const int tid   = threadIdx.x;
    const int q     = tid & 3;
    const int c     = tid >> 2;
    const int j0    = 4 * c;
    const int kbase = 128 * q;
    const int b     = blockIdx.x;

    half2_t wr[K4_NW];
    uint4*  myW = ldsW + tid * K4_STR;
#pragma unroll
    for (int p = 0; p < K4_RP; ++p) {
        const float4 f0 = *reinterpret_cast<const float4*>(Whh + (size_t)(kbase + 2 * p) * HDIM + j0);
        const float4 f1 = *reinterpret_cast<const float4*>(Whh + (size_t)(kbase + 2 * p + 1) * HDIM + j0);
        half2_t w;
        w[0] = (_Float16)f0.x; w[1] = (_Float16)f1.x; wr[4 * p + 0] = w;
        w[0] = (_Float16)f0.y; w[1] = (_Float16)f1.y; wr[4 * p + 1] = w;
        w[0] = (_Float16)f0.z; w[1] = (_Float16)f1.z; wr[4 * p + 2] = w;
        w[0] = (_Float16)f0.w; w[1] = (_Float16)f1.w; wr[4 * p + 3] = w;
    }
#pragma unroll
    for (int cc = 0; cc < 4; ++cc) {
        H8U t0, t1, t2, t3;
#pragma unroll
        for (int e = 0; e < 4; ++e) {
            const int k = kbase + 96 + 8 * cc + 2 * e;
            const float4 f0 = *reinterpret_cast<const float4*>(Whh + (size_t)k * HDIM + j0);
            const float4 f1 = *reinterpret_cast<const float4*>(Whh + (size_t)(k + 1) * HDIM + j0);
            half2_t w;
            w[0] = (_Float16)f0.x; w[1] = (_Float16)f1.x; t0.p[e] = w;
            w[0] = (_Float16)f0.y; w[1] = (_Float16)f1.y; t1.p[e] = w;
            w[0] = (_Float16)f0.z; w[1] = (_Float16)f1.z; t2.p[e] = w;
            w[0] = (_Float16)f0.w; w[1] = (_Float16)f1.w; t3.p[e] = w;
        }
        myW[cc] = t0.u4; myW[4 + cc] = t1.u4; myW[8 + cc] = t2.u4; myW[12 + cc] = t3.u4;
    }

    const char* hb0c = smem + K4_HB_OFF + 288 * q;
    const char* hb1c = hb0c + K4_HB_STRIDE;
    const int   jw    = j0 + q;
    const int   wbyte = 2 * jw + 32 * (jw >> 7);
    _Float16* wp0 = reinterpret_cast<_Float16*>(smem + K4_HB_OFF + wbyte);
    _Float16* wp1 = reinterpret_cast<_Float16*>(smem + K4_HB_OFF + K4_HB_STRIDE + wbyte);

    const float fcwj = fcw[jw];
    const _Float16* xhp = xh + (size_t)b * TSTEPS * HDIM + jw;

    if (tid < 144) {
        uint4 z; z.x = z.y = z.z = z.w = 0u;
        reinterpret_cast<uint4*>(smem + K4_HB_OFF)[tid] = z;
    }
    __syncthreads();

    float hlast = 0.f;
#pragma unroll 1
    for (int t = 0; t < TSTEPS; ++t) {
        const _Float16* hb = reinterpret_cast<const _Float16*>((t & 1) ? hb1c : hb0c);
        const float xv = (float)*xhp;
        xhp += HDIM;

        float a0 = 0.f, b0 = 0.f, a1 = 0.f, b1 = 0.f;
        float a2 = 0.f, b2 = 0.f, a3 = 0.f, b3 = 0.f;
#pragma unroll
        for (int i = 0; i < 12; ++i) {
            H8U u; u.v = *reinterpret_cast<const half8_t*>(hb + 8 * i);
            a0 = fdot2(u.p[0], wr[16*i +  0], a0);
            a1 = fdot2(u.p[0], wr[16*i +  1], a1);
            a2 = fdot2(u.p[0], wr[16*i +  2], a2);
            a3 = fdot2(u.p[0], wr[16*i +  3], a3);
            b0 = fdot2(u.p[1], wr[16*i +  4], b0);
            b1 = fdot2(u.p[1], wr[16*i +  5], b1);
            b2 = fdot2(u.p[1], wr[16*i +  6], b2);
            b3 = fdot2(u.p[1], wr[16*i +  7], b3);
            a0 = fdot2(u.p[2], wr[16*i +  8], a0);
            a1 = fdot2(u.p[2], wr[16*i +  9], a1);
            a2 = fdot2(u.p[2], wr[16*i + 10], a2);
            a3 = fdot2(u.p[2], wr[16*i + 11], a3);
            b0 = fdot2(u.p[3], wr[16*i + 12], b0);
            b1 = fdot2(u.p[3], wr[16*i + 13], b1);
            b2 = fdot2(u.p[3], wr[16*i + 14], b2);
            b3 = fdot2(u.p[3], wr[16*i + 15], b3);
        }
#pragma unroll
        for (int cc = 0; cc < 4; ++cc) {
            H8U u; u.v = *reinterpret_cast<const half8_t*>(hb + 8 * (12 + cc));
            H8U w0; w0.u4 = myW[cc];
            H8U w1; w1.u4 = myW[4 + cc];
            H8U w2; w2.u4 = myW[8 + cc];
            H8U w3; w3.u4 = myW[12 + cc];
            a0 = fdot2(u.p[0], w0.p[0], a0); b0 = fdot2(u.p[1], w0.p[1], b0);
            a0 = fdot2(u.p[2], w0.p[2], a0); b0 = fdot2(u.p[3], w0.p[3], b0);
            a1 = fdot2(u.p[0], w1.p[0], a1); b1 = fdot2(u.p[1], w1.p[1], b1);
            a1 = fdot2(u.p[2], w1.p[2], a1); b1 = fdot2(u.p[3], w1.p[3], b1);
            a2 = fdot2(u.p[0], w2.p[0], a2); b2 = fdot2(u.p[1], w2.p[1], b2);
            a2 = fdot2(u.p[2], w2.p[2], a2); b2 = fdot2(u.p[3], w2.p[3], b2);
            a3 = fdot2(u.p[0], w3.p[0], a3); b3 = fdot2(u.p[1], w3.p[1], b3);
            a3 = fdot2(u.p[2], w3.p[2], a3); b3 = fdot2(u.p[3], w3.p[3], b3);
        }

        const float s0 = quad_sum(a0 + b0);
        const float s1 = quad_sum(a1 + b1);
        const float s2 = quad_sum(a2 + b2);
        const float s3 = quad_sum(a3 + b3);

        const float sq = (q & 2) ? ((q & 1) ? s3 : s2) : ((q & 1) ? s1 : s0);
        const float h  = fast_tanh(sq + xv);
        *((t & 1) ? wp0 : wp1) = (_Float16)h;
        hlast = h;
        __syncthreads();
    }

    float partial = hlast * fcwj;
#pragma unroll
    for (int off = 32; off >= 1; off >>= 1)
        partial += __shfl_down(partial, off, 64);
    if ((tid & 63) == 0) red[tid >> 6] = partial;
    __syncthreads();
    if (tid == 0) {
        float s = 0.f;
#pragma unroll
        for (int w2 = 0; w2 < 8; ++w2) s += red[w2];
        out[b] = s + fcb[0];
    }
}

// ============================= fused fallback (K=576, unchanged) =============================
#define F_RP   216
#define F_RC   54
#define F_LC   18
#define F_LSTR 19
#define F_LDSW_BYTES (512 * F_LSTR * 16)
#define F_HBUF_OFF   F_LDSW_BYTES
#define F_HBUF_ELEMS 640
#define F_RED_OFF    (F_HBUF_OFF + 2 * F_HBUF_ELEMS * 2)
#define F_SMEM_BYTES (F_RED_OFF + 64)

__global__ __attribute__((amdgpu_flat_work_group_size(NTH, NTH), amdgpu_waves_per_eu(2, 2)))
void rnn_fused(const float* __restrict__ x, const float* __restrict__ Wxh,
               const float* __restrict__ Whh, const float* __restrict__ bias,
               const float* __restrict__ fcw, const float* __restrict__ fcb,
               float* __restrict__ out)
{
    extern __shared__ char smem[];
    uint4*    ldsW = reinterpret_cast<uint4*>(smem);
    _Float16* hbuf = reinterpret_cast<_Float16*>(smem + F_HBUF_OFF);
    float*    red  = reinterpret_cast<float*>(smem + F_RED_OFF);

    const int j = threadIdx.x;
    const int b = blockIdx.x;

    half2_t wreg[F_RP];
#pragma unroll
    for (int p = 0; p < F_RP; ++p) {
        const int k = 2 * p;
        half2_t w;
        w[0] = (_Float16)Whh[(size_t)k * HDIM + j];
        w[1] = (_Float16)Whh[(size_t)(k + 1) * HDIM + j];
        wreg[p] = w;
    }
#pragma unroll
    for (int cc = 0; cc < F_LC; ++cc) {
        H8U u;
#pragma unroll
        for (int qq = 0; qq < 4; ++qq) {
            const int k0 = 432 + 8 * cc + 2 * qq;
            const int k1 = k0 + 1;
            half2_t w;
            w[0] = (_Float16)(k0 < HDIM ? Whh[(size_t)k0 * HDIM + j]
                                        : Wxh[(size_t)(k0 - HDIM) * HDIM + j]);
            w[1] = (_Float16)(k1 < HDIM ? Whh[(size_t)k1 * HDIM + j]
                                        : Wxh[(size_t)(k1 - HDIM) * HDIM + j]);
            u.p[qq] = w;
        }
        ldsW[j * F_LSTR + cc] = u.u4;
    }

    const float bj   = bias[j];
    const float fcwj = fcw[j];

    hbuf[j] = (_Float16)0.0f;
    if (j < IDIM) hbuf[HDIM + j] = (_Float16)x[((size_t)b * TSTEPS + 0) * IDIM + j];
    __syncthreads();

    float hval = 0.0f;
    for (int t = 0; t < TSTEPS; ++t) {
        const int cur = t & 1;
        const int nxt = cur ^ 1;
        const _Float16* hb = hbuf + cur * F_HBUF_ELEMS;

        float xv = 0.0f;
        const bool do_x = (j < IDIM) && (t + 1 < TSTEPS);
        if (do_x) xv = x[((size_t)b * TSTEPS + (t + 1)) * IDIM + j];

        float a0 = bj, a1 = 0.0f, a2 = 0.0f, a3 = 0.0f;
#pragma unroll
        for (int c = 0; c < F_RC; ++c) {
            H8U u;
            u.v = *reinterpret_cast<const half8_t*>(hb + 8 * c);
            a0 = fdot2(u.p[0], wreg[4 * c + 0], a0);
            a1 = fdot2(u.p[1], wreg[4 * c + 1], a1);
            a2 = fdot2(u.p[2], wreg[4 * c + 2], a2);
            a3 = fdot2(u.p[3], wreg[4 * c + 3], a3);
        }
#pragma unroll
        for (int cc = 0; cc < F_LC; ++cc) {
            H8U u, w;
            u.v  = *reinterpret_cast<const half8_t*>(hb + 8 * (F_RC + cc));
            w.u4 = ldsW[j * F_LSTR + cc];
            a0 = fdot2(u.p[0], w.p[0], a0);
            a1 = fdot2(u.p[1], w.p[1], a1);
            a2 = fdot2(u.p[2], w.p[2], a2);
            a3 = fdot2(u.p[3], w.p[3], a3);
        }
        hval = fast_tanh((a0 + a1) + (a2 + a3));

        hbuf[nxt * F_HBUF_ELEMS + j] = (_Float16)hval;
        if (do_x) hbuf[nxt * F_HBUF_ELEMS + HDIM + j] = (_Float16)xv;
        __syncthreads();
    }

    float partial = hval * fcwj;
#pragma unroll
    for (int off = 32; off >= 1; off >>= 1)
        partial += __shfl_down(partial, off, 64);
    if ((j & 63) == 0) red[j >> 6] = partial;
    __syncthreads();
    if (j == 0) {
        float s = 0.0f;
#pragma unroll
        for (int w2 = 0; w2 < 8; ++w2) s += red[w2];
        out[b] = s + fcb[0];
    }
}

// ============================= host =============================
extern "C" void kernel_launch(void* const* d_in, const int* in_sizes, int n_in,
                              void* d_out, int out_size, void* d_ws, size_t ws_size,
                              hipStream_t stream) {
    const float* x    = (const float*)d_in[0];
    const float* Wxh  = (const float*)d_in[1];
    const float* Whh  = (const float*)d_in[2];
    const float* bias = (const float*)d_in[3];
    const float* fcw  = (const float*)d_in[4];
    const float* fcb  = (const float*)d_in[5];
    float* out = (float*)d_out;

    const size_t xh_bytes = (size_t)BATCH * TSTEPS * HDIM * sizeof(_Float16);  // 134 MB
    const size_t wt_bytes = (size_t)HDIM * HDIM * sizeof(_Float16);            // 512 KB

    if (ws_size >= xh_bytes + wt_bytes) {
        _Float16* xh = (_Float16*)d_ws;
        _Float16* wt = (_Float16*)((char*)d_ws + xh_bytes);
        wt_prep<<<(NJT * KT * 64) / NTH, NTH, 0, stream>>>(Whh, wt);
        xh_gemm<<<(BATCH * TSTEPS) / XH_ROWS, NTH, 0, stream>>>(x, Wxh, bias, xh);
        rnn_mfma<<<NBLK, NTH, 0, stream>>>(xh, wt, fcw, fcb, out);
    } else if (ws_size >= xh_bytes) {
        hipFuncSetAttribute(reinterpret_cast<const void*>(rnn_k4s),
                            hipFuncAttributeMaxDynamicSharedMemorySize, K4_SMEM_BYTES);
        _Float16* xh = (_Float16*)d_ws;
        xh_gemm<<<(BATCH * TSTEPS) / XH_ROWS, NTH, 0, stream>>>(x, Wxh, bias, xh);
        rnn_k4s<<<BATCH, NTH, K4_SMEM_BYTES, stream>>>(xh, Whh, fcw, fcb, out);
    } else {
        hipFuncSetAttribute(reinterpret_cast<const void*>(rnn_fused),
                            hipFuncAttributeMaxDynamicSharedMemorySize, F_SMEM_BYTES);
        rnn_fused<<<BATCH, NTH, F_SMEM_BYTES, stream>>>(x, Wxh, Whh, bias, fcw, fcb, out);
    }
}